// Round 5
// baseline (119.490 us; speedup 1.0000x reference)
//
#include <hip/hip_runtime.h>
#include <hip/hip_fp16.h>

// MinEuclideanDistBlock: out[b,n] = min_w sum_c sqrt(max(||win||^2+||shp||^2-2*cross,0))
// B=64,C=3,L=2048,N=256,S=64,W=1985.
// R5: diagnosis from R2-R4: compiler pinned VGPR=64 (8-wave target) and spilled the
// ~100-reg hot-loop live set; also memcpy loads from u16* couldn't prove 16B alignment.
// Fixes: amdgpu_waves_per_eu(4,4) pins a 128-reg budget (no spills); prep writes 8
// shifted bf16 copies of x so every A-frag is ONE aligned global_load_dwordx4 (typed);
// hw stored f32 and loaded as aligned v4f (no f16 cvts). No LDS in hot loop, no
// branches (sentinel hw=-1e30 masks w>=1985). Grid 1024 = 64b x 8nt(32n) x 2wh(1024w),
// 4 waves, wave tile 32w x 32n, 8 iters. acc init = hw+hs (pre-scaled -0.5) so
// acc=-d2/2; d/sqrt2 = sqrt(max(-acc,0)); sqrt2 after the min. u32 atomicMin combine.

typedef float  v4f __attribute__((ext_vector_type(4)));
typedef unsigned int v4u __attribute__((ext_vector_type(4)));
typedef short  v8s __attribute__((ext_vector_type(8)));
typedef unsigned short u16;
typedef unsigned int   u32;
typedef unsigned long long u64;

#define N_ 256
#define C_ 3
#define L_ 2048
#define W_ 1985
#define XROW 2112          // elements per shifted copy (264 16B-units, 16B-aligned rows)

// d_ws byte offsets
#define OFF_GX   0u               // [192][8][2112] u16 = 6,488,064 B
#define OFF_HW   6488064u         // [192][2048] f32    = 1,572,864 B
#define OFF_SHP  8060928u         // [3][256][64] u16   =    98,304 B
#define OFF_HS   8159232u         // [768] f32          =     3,072 B

__device__ __forceinline__ u16 f2bf(float f) {
    u32 u = __builtin_bit_cast(u32, f);
    return (u16)((u + 0x7FFFu + ((u >> 16) & 1u)) >> 16);
}
__device__ __forceinline__ float bf2f(u16 b) {
    return __builtin_bit_cast(float, ((u32)b) << 16);
}
__device__ __forceinline__ u64 pack4(v4f v) {
    return (u64)f2bf(v[0]) | ((u64)f2bf(v[1]) << 16)
         | ((u64)f2bf(v[2]) << 32) | ((u64)f2bf(v[3]) << 48);
}

//============================ PREP ============================
// blocks 0..383: (bc = blk>>1, which = blk&1) -> 4 shifted copies each; which==1 also
// writes hw. 384..386: shapelet tasks. 387..450: out init.
__global__ __launch_bounds__(256)
void prep_kernel(const float* __restrict__ x, const float* __restrict__ shp,
                 u16* __restrict__ gx, float* __restrict__ ghw,
                 u16* __restrict__ gshp, float* __restrict__ ghs,
                 u32* __restrict__ out_u)
{
    const int blk = blockIdx.x, tid = threadIdx.x;
    if (blk < 384) {
        __shared__ u16 xb[2176];                 // bf16 row + 128 zero pad
        const int bc = blk >> 1, which = blk & 1;
        const float* xr = x + (size_t)bc * L_;
        v4f a0 = *(const v4f*)(xr + tid * 8);
        v4f a1 = *(const v4f*)(xr + tid * 8 + 4);
        ((u64*)xb)[tid * 2]     = pack4(a0);
        ((u64*)xb)[tid * 2 + 1] = pack4(a1);
        if (tid < 32) ((u64*)xb)[512 + tid] = 0;
        __syncthreads();

        // 4 of the 8 shifted copies: copy r holds x[j+r] at element j (zero-padded)
        const u32* lw = (const u32*)xb;
        #pragma unroll 1
        for (int i = 0; i < 5; ++i) {
            int idx = tid + i * 256;
            if (idx < 1056) {                    // 4 copies x 264 16B-units
                int rr = idx >> 8;               // hmm: need idx/264 -- do it exactly:
                rr = idx / 264;
                int u  = idx - rr * 264;
                int r  = which * 4 + rr;
                int base = (8 * u + r) >> 1;     // u32 word index of first element
                u32 w0 = lw[base], w1 = lw[base + 1], w2 = lw[base + 2], w3 = lw[base + 3];
                v4u o;
                if (r & 1) {
                    u32 w4 = lw[base + 4];
                    o[0] = (w0 >> 16) | (w1 << 16);
                    o[1] = (w1 >> 16) | (w2 << 16);
                    o[2] = (w2 >> 16) | (w3 << 16);
                    o[3] = (w3 >> 16) | (w4 << 16);
                } else { o[0] = w0; o[1] = w1; o[2] = w2; o[3] = w3; }
                *(v4u*)(gx + ((size_t)bc * 8 + r) * XROW + u * 8) = o;
            }
        }
        // hw = -0.5*||win||^2 (f32) with sentinel -1e30 for w>=1985 (arithmetic mask)
        if (which == 1) {
            float e[72];
            #pragma unroll
            for (int j = 0; j < 18; ++j) {
                u64 ch = ((const u64*)xb)[tid * 2 + j];
                e[j * 4 + 0] = bf2f((u16)(ch));
                e[j * 4 + 1] = bf2f((u16)(ch >> 16));
                e[j * 4 + 2] = bf2f((u16)(ch >> 32));
                e[j * 4 + 3] = bf2f((u16)(ch >> 48));
            }
            float s = 0.f;
            #pragma unroll
            for (int i = 0; i < 64; ++i) s += e[i] * e[i];
            const int w0 = tid * 8;
            float hv[8];
            hv[0] = (w0 < W_) ? -0.5f * s : -1e30f;
            #pragma unroll
            for (int k = 1; k < 8; ++k) {
                s += e[63 + k] * e[63 + k] - e[k - 1] * e[k - 1];
                hv[k] = (w0 + k < W_) ? -0.5f * s : -1e30f;
            }
            float* dst = ghw + (size_t)bc * L_ + w0;
            *(v4f*)dst       = (v4f){hv[0], hv[1], hv[2], hv[3]};
            *(v4f*)(dst + 4) = (v4f){hv[4], hv[5], hv[6], hv[7]};
        }
    } else if (blk < 387) {
        const int c = blk - 384;
        const int n = tid;
        const float* row = shp + ((size_t)c * N_ + n) * 64;
        float sacc = 0.f;
        #pragma unroll
        for (int k = 0; k < 8; ++k) {
            v4f a0 = *(const v4f*)(row + k * 8);
            v4f a1 = *(const v4f*)(row + k * 8 + 4);
            u64 p0 = pack4(a0), p1 = pack4(a1);
            union { u64 u[2]; v4u v; } st; st.u[0] = p0; st.u[1] = p1;
            *(v4u*)(gshp + ((size_t)c * N_ + n) * 64 + k * 8) = st.v;
            #pragma unroll
            for (int j = 0; j < 4; ++j) {
                float e0 = bf2f((u16)(p0 >> (16 * j)));
                float e1 = bf2f((u16)(p1 >> (16 * j)));
                sacc += e0 * e0 + e1 * e1;
            }
        }
        ghs[c * N_ + n] = -0.5f * sacc;
    } else {
        int i = (blk - 387) * 256 + tid;         // exactly 16384
        out_u[i] = 0x7F800000u;                  // +inf
    }
}

//============================ MAIN ============================
__global__ __attribute__((amdgpu_waves_per_eu(4, 4))) __launch_bounds__(256)
void shapelet_min_kernel(const u16* __restrict__ gx, const float* __restrict__ ghw,
                         const u16* __restrict__ gshp, const float* __restrict__ ghs,
                         u32* __restrict__ out_u)
{
    __shared__ float red[4][32];

    const int tid  = threadIdx.x;
    const int wave = tid >> 6;
    const int lane = tid & 63;
    const int m    = lane & 15;
    const int q    = lane >> 4;
    const int r    = m & 7;          // which shifted copy; (m-r) in {0,8} keeps 16B align
    const int wh   = blockIdx.x & 1;
    const int nb   = (blockIdx.x >> 1) & 7;
    const int b    = blockIdx.x >> 4;
    const int n0   = nb << 5;
    const int wstart = wh << 10;

    // B fragments + hs from global (L2-resident, loop-invariant)
    v8s   bfr[C_][2][2];
    float hs[C_][2];
    #pragma unroll
    for (int c = 0; c < C_; ++c)
        #pragma unroll
        for (int nt = 0; nt < 2; ++nt) {
            int n = n0 + nt * 16 + m;
            hs[c][nt] = ghs[c * N_ + n];
            #pragma unroll
            for (int h = 0; h < 2; ++h)
                bfr[c][nt][h] = *(const v8s*)(gshp + ((size_t)(c * N_ + n) * 64 + h * 32 + q * 8));
        }

    // per-c bases; all per-iter deltas are 13-bit immediate offsets
    const u16*   pa[C_];
    const float* pw[C_];
    #pragma unroll
    for (int c = 0; c < C_; ++c) {
        pa[c] = gx  + ((size_t)(b * 3 + c) * 8 + r) * XROW + (wstart + wave * 32 + (m - r) + q * 8);
        pw[c] = ghw + (size_t)(b * 3 + c) * L_ + (wstart + wave * 32 + q * 4);
    }

    float mins[2] = {1e30f, 1e30f};

    #pragma unroll 1
    for (int it = 0; it < 8; ++it) {
        const int iof = it * 128;
        float sums[2][2][4];
        #pragma unroll
        for (int mt = 0; mt < 2; ++mt)
            #pragma unroll
            for (int nt = 0; nt < 2; ++nt)
                #pragma unroll
                for (int g = 0; g < 4; ++g) sums[mt][nt][g] = 0.f;

        #pragma unroll
        for (int c = 0; c < C_; ++c) {
            // acc init = hw + hs (both pre-scaled -0.5); sentinel hw kills padded w
            v4f hwv[2];
            #pragma unroll
            for (int mt = 0; mt < 2; ++mt)
                hwv[mt] = *(const v4f*)(pw[c] + iof + mt * 16);   // aligned dwordx4
            v4f acc[2][2];
            #pragma unroll
            for (int mt = 0; mt < 2; ++mt)
                #pragma unroll
                for (int g = 0; g < 4; ++g) {
                    acc[mt][0][g] = hwv[mt][g] + hs[c][0];
                    acc[mt][1][g] = hwv[mt][g] + hs[c][1];
                }
            #pragma unroll
            for (int h = 0; h < 2; ++h) {
                v8s afr[2];
                #pragma unroll
                for (int mt = 0; mt < 2; ++mt) {
                    v4u av = *(const v4u*)(pa[c] + iof + mt * 16 + h * 32);  // aligned dwordx4
                    afr[mt] = __builtin_bit_cast(v8s, av);
                }
                #pragma unroll
                for (int mt = 0; mt < 2; ++mt)
                    #pragma unroll
                    for (int nt = 0; nt < 2; ++nt)
                        acc[mt][nt] = __builtin_amdgcn_mfma_f32_16x16x32_bf16(
                            afr[mt], bfr[c][nt][h], acc[mt][nt], 0, 0, 0);
            }
            // acc = -d2/2; d/sqrt2 = sqrt(max(-acc,0)); accumulate over channels
            #pragma unroll
            for (int mt = 0; mt < 2; ++mt)
                #pragma unroll
                for (int nt = 0; nt < 2; ++nt)
                    #pragma unroll
                    for (int g = 0; g < 4; ++g)
                        sums[mt][nt][g] += __builtin_amdgcn_sqrtf(fmaxf(-acc[mt][nt][g], 0.f));
        }
        #pragma unroll
        for (int mt = 0; mt < 2; ++mt)
            #pragma unroll
            for (int nt = 0; nt < 2; ++nt)
                #pragma unroll
                for (int g = 0; g < 4; ++g)
                    mins[nt] = fminf(mins[nt], sums[mt][nt][g]);
    }

    //=== Reduce across quads (same n, different w-rows), waves, then atomicMin ===
    #pragma unroll
    for (int nt = 0; nt < 2; ++nt) {
        mins[nt] = fminf(mins[nt], __shfl_xor(mins[nt], 16));
        mins[nt] = fminf(mins[nt], __shfl_xor(mins[nt], 32));
    }
    if (lane < 16) { red[wave][m] = mins[0]; red[wave][16 + m] = mins[1]; }
    __syncthreads();
    if (tid < 32) {
        float v = fminf(fminf(red[0][tid], red[1][tid]),
                        fminf(red[2][tid], red[3][tid]));
        atomicMin(out_u + (size_t)b * N_ + n0 + tid,
                  __float_as_uint(v * 1.41421356237f));
    }
}

extern "C" void kernel_launch(void* const* d_in, const int* in_sizes, int n_in,
                              void* d_out, int out_size, void* d_ws, size_t ws_size,
                              hipStream_t stream) {
    const float* x   = (const float*)d_in[0];   // (64, 3, 2048) fp32
    const float* shp = (const float*)d_in[1];   // (3, 256, 64) fp32
    u32* out_u       = (u32*)d_out;             // (64, 1, 256) fp32 via u32 atomicMin

    char* ws = (char*)d_ws;
    u16*   gx   = (u16*)(ws + OFF_GX);
    float* ghw  = (float*)(ws + OFF_HW);
    u16*   gshp = (u16*)(ws + OFF_SHP);
    float* ghs  = (float*)(ws + OFF_HS);

    hipLaunchKernelGGL(prep_kernel, dim3(451), dim3(256), 0, stream,
                       x, shp, gx, ghw, gshp, ghs, out_u);
    hipLaunchKernelGGL(shapelet_min_kernel, dim3(1024), dim3(256), 0, stream,
                       gx, ghw, gshp, ghs, out_u);
}

// Round 6
// 105.788 us; speedup vs baseline: 1.1295x; 1.1295x over previous
//
#include <hip/hip_runtime.h>
#include <hip/hip_fp16.h>

// MinEuclideanDistBlock: out[b,n] = min_w sum_c sqrt(max(||win||^2+||shp||^2-2*cross,0))
// B=64,C=3,L=2048,N=256,S=64,W=1985.
// R6: diagnosis: compiler gives only 64 ARCH VGPRs (rest of budget goes to AGPRs),
// so loads can't stay in flight -> latency-bound at 25-40% on all pipes.
// Fixes: amdgpu_waves_per_eu(2,2) -> 256-reg waves, 2/SIMD, deep load pipelining;
// wave tile 32w x 64n (nt=4) halves A-duplication; BOTH norms folded into MFMA:
// per-w A-norm frag [1,hw_hi,hw_lo,1] (prep table, sentinel -1e30 masks w>=1985) and
// B-norm frag [hs_hi,1,1,hs_lo] (q==0 lanes only; zero B kills garbage A k>=8 cols),
// so acc = -d2/2 directly out of the MFMA chain (no acc-init adds, no hw loads).
// Grid 512 = 64b x 4ng(64n) x 2wh(1024w); 4 waves; 8 iters. d = sqrt2*sqrt(max(-acc,0)),
// sqrt2 applied once after the min. Cross-block combine via u32 atomicMin on +floats.

typedef float  v4f __attribute__((ext_vector_type(4)));
typedef unsigned int v4u __attribute__((ext_vector_type(4)));
typedef short  v8s __attribute__((ext_vector_type(8)));
typedef unsigned short u16;
typedef unsigned int   u32;
typedef unsigned long long u64;

#define N_ 256
#define C_ 3
#define L_ 2048
#define W_ 1985
#define XROW 2112          // elements per shifted copy (264 16B-units, 16B-aligned rows)

// d_ws byte offsets
#define OFF_GX   0u               // [192][8][2112] u16      = 6,488,064 B
#define OFF_NORM 6488064u         // [192][2048] x 8 u16     = 6,291,456 B
#define OFF_SHP  12779520u        // [3][256][64] u16 (bf16) =    98,304 B
#define OFF_HS   12877824u        // [768] f32               =     3,072 B

__device__ __forceinline__ u16 f2bf(float f) {
    u32 u = __builtin_bit_cast(u32, f);
    return (u16)((u + 0x7FFFu + ((u >> 16) & 1u)) >> 16);
}
__device__ __forceinline__ float bf2f(u16 b) {
    return __builtin_bit_cast(float, ((u32)b) << 16);
}
__device__ __forceinline__ u64 pack4(v4f v) {
    return (u64)f2bf(v[0]) | ((u64)f2bf(v[1]) << 16)
         | ((u64)f2bf(v[2]) << 32) | ((u64)f2bf(v[3]) << 48);
}

//============================ PREP ============================
// blocks 0..383: (bc = blk>>1, which = blk&1): 4 shifted copies each; which==1 also
// writes the A-norm table. 384..386: shapelet tasks. 387..450: out init.
__global__ __launch_bounds__(256)
void prep_kernel(const float* __restrict__ x, const float* __restrict__ shp,
                 u16* __restrict__ gx, u16* __restrict__ gnorm,
                 u16* __restrict__ gshp, float* __restrict__ ghs,
                 u32* __restrict__ out_u)
{
    const int blk = blockIdx.x, tid = threadIdx.x;
    if (blk < 384) {
        __shared__ u16 xb[2176];                 // bf16 row + 128 zero pad
        const int bc = blk >> 1, which = blk & 1;
        const float* xr = x + (size_t)bc * L_;
        v4f a0 = *(const v4f*)(xr + tid * 8);
        v4f a1 = *(const v4f*)(xr + tid * 8 + 4);
        ((u64*)xb)[tid * 2]     = pack4(a0);
        ((u64*)xb)[tid * 2 + 1] = pack4(a1);
        if (tid < 32) ((u64*)xb)[512 + tid] = 0;
        __syncthreads();

        // 4 of the 8 shifted copies: copy r holds x[j+r] at element j (zero-padded)
        const u32* lw = (const u32*)xb;
        #pragma unroll 1
        for (int i = 0; i < 5; ++i) {
            int idx = tid + i * 256;
            if (idx < 1056) {                    // 4 copies x 264 16B-units
                int rr = idx / 264;
                int u  = idx - rr * 264;
                int r  = which * 4 + rr;
                int base = (8 * u + r) >> 1;     // u32 word index of first element
                u32 w0 = lw[base], w1 = lw[base + 1], w2 = lw[base + 2], w3 = lw[base + 3];
                v4u o;
                if (r & 1) {
                    u32 w4 = lw[base + 4];
                    o[0] = (w0 >> 16) | (w1 << 16);
                    o[1] = (w1 >> 16) | (w2 << 16);
                    o[2] = (w2 >> 16) | (w3 << 16);
                    o[3] = (w3 >> 16) | (w4 << 16);
                } else { o[0] = w0; o[1] = w1; o[2] = w2; o[3] = w3; }
                *(v4u*)(gx + ((size_t)bc * 8 + r) * XROW + u * 8) = o;
            }
        }
        // A-norm table: entry w = [1, hw_hi, hw_lo, 1, 0,0,0,0] bf16, hw = -0.5*||win_w||^2
        // (hi/lo split for precision); sentinel hw = -1e30 for w >= 1985.
        if (which == 1) {
            float e[72];
            #pragma unroll
            for (int j = 0; j < 18; ++j) {
                u64 ch = ((const u64*)xb)[tid * 2 + j];
                e[j * 4 + 0] = bf2f((u16)(ch));
                e[j * 4 + 1] = bf2f((u16)(ch >> 16));
                e[j * 4 + 2] = bf2f((u16)(ch >> 32));
                e[j * 4 + 3] = bf2f((u16)(ch >> 48));
            }
            float s = 0.f;
            #pragma unroll
            for (int i = 0; i < 64; ++i) s += e[i] * e[i];
            const int w0 = tid * 8;
            u16* gn = gnorm + ((size_t)bc * 2048 + w0) * 8;
            float scur = s;
            #pragma unroll
            for (int k = 0; k < 8; ++k) {
                if (k) scur += e[63 + k] * e[63 + k] - e[k - 1] * e[k - 1];
                float hv = (w0 + k < W_) ? -0.5f * scur : -1e30f;
                u16 hi = f2bf(hv);
                u16 lo = f2bf(hv - bf2f(hi));
                v4u o;
                o[0] = 0x3F80u | ((u32)hi << 16);
                o[1] = (u32)lo | (0x3F80u << 16);
                o[2] = 0; o[3] = 0;
                *(v4u*)(gn + k * 8) = o;
            }
        }
    } else if (blk < 387) {
        const int c = blk - 384;
        const int n = tid;
        const float* row = shp + ((size_t)c * N_ + n) * 64;
        float sacc = 0.f;
        #pragma unroll
        for (int k = 0; k < 8; ++k) {
            v4f a0 = *(const v4f*)(row + k * 8);
            v4f a1 = *(const v4f*)(row + k * 8 + 4);
            u64 p0 = pack4(a0), p1 = pack4(a1);
            union { u64 u[2]; v4u v; } st; st.u[0] = p0; st.u[1] = p1;
            *(v4u*)(gshp + ((size_t)c * N_ + n) * 64 + k * 8) = st.v;
            #pragma unroll
            for (int j = 0; j < 4; ++j) {
                float e0 = bf2f((u16)(p0 >> (16 * j)));
                float e1 = bf2f((u16)(p1 >> (16 * j)));
                sacc += e0 * e0 + e1 * e1;
            }
        }
        ghs[c * N_ + n] = -0.5f * sacc;
    } else {
        int i = (blk - 387) * 256 + tid;         // exactly 16384
        out_u[i] = 0x7F800000u;                  // +inf
    }
}

//============================ MAIN ============================
__global__ __attribute__((amdgpu_waves_per_eu(2, 2))) __launch_bounds__(256)
void shapelet_min_kernel(const u16* __restrict__ gx, const u16* __restrict__ gnorm,
                         const u16* __restrict__ gshp, const float* __restrict__ ghs,
                         u32* __restrict__ out_u)
{
    __shared__ float red[4][64];

    const int tid  = threadIdx.x;
    const int wave = tid >> 6;
    const int lane = tid & 63;
    const int m    = lane & 15;
    const int q    = lane >> 4;
    const int r    = m & 7;          // which shifted copy; (m-r) in {0,8} keeps 16B align
    const int wh   = blockIdx.x & 1;
    const int ng   = (blockIdx.x >> 1) & 3;
    const int b    = blockIdx.x >> 3;
    const int n0   = ng << 6;        // 64-wide n tile
    const int wv   = (wh << 10) + wave * 32;

    // B data fragments (24 v8s -> AGPRs) + B norm fragments [hs_hi,1,1,hs_lo] (q==0 only)
    v8s bfr[C_][4][2];
    v8s bnorm[C_][4];
    const v8s z8 = {0, 0, 0, 0, 0, 0, 0, 0};
    #pragma unroll
    for (int c = 0; c < C_; ++c)
        #pragma unroll
        for (int nt = 0; nt < 4; ++nt) {
            int n = n0 + nt * 16 + m;
            float hsf = ghs[c * N_ + n];
            u16 hi = f2bf(hsf);
            u16 lo = f2bf(hsf - bf2f(hi));
            union { u64 u[2]; v8s v; } bn;
            bn.u[0] = (u64)hi | (0x3F80ULL << 16) | (0x3F80ULL << 32) | ((u64)lo << 48);
            bn.u[1] = 0;
            bnorm[c][nt] = (q == 0) ? bn.v : z8;
            #pragma unroll
            for (int h = 0; h < 2; ++h)
                bfr[c][nt][h] = *(const v8s*)(gshp + ((size_t)(c * N_ + n) * 64 + h * 32 + q * 8));
        }

    // per-c bases
    const u16* pa[C_];
    const u16* pn[C_];
    #pragma unroll
    for (int c = 0; c < C_; ++c) {
        pa[c] = gx + ((size_t)(b * 3 + c) * 8 + r) * XROW + (wv + (m - r) + q * 8);
        pn[c] = gnorm + ((size_t)(b * 3 + c) * 2048 + wv + m) * 8;
    }

    float mins[4] = {1e30f, 1e30f, 1e30f, 1e30f};
    const v4f z4 = {0.f, 0.f, 0.f, 0.f};

    #pragma unroll 1
    for (int it = 0; it < 8; ++it) {
        float sums[2][4][4];
        #pragma unroll
        for (int mt = 0; mt < 2; ++mt)
            #pragma unroll
            for (int nt = 0; nt < 4; ++nt)
                #pragma unroll
                for (int g = 0; g < 4; ++g) sums[mt][nt][g] = 0.f;

        #pragma unroll
        for (int c = 0; c < C_; ++c) {
            // 6 aligned dwordx4 loads: 2 norm frags + 4 data frags
            v8s an[2], af[2][2];
            #pragma unroll
            for (int mt = 0; mt < 2; ++mt) {
                v4u t = *(const v4u*)(pn[c] + it * 1024 + mt * 128);
                an[mt] = __builtin_bit_cast(v8s, t);
                #pragma unroll
                for (int h = 0; h < 2; ++h) {
                    v4u u = *(const v4u*)(pa[c] + it * 128 + mt * 16 + h * 32);
                    af[mt][h] = __builtin_bit_cast(v8s, u);
                }
            }
            // acc = (hw + hs) - cross  (all pre-scaled by -0.5) => acc = -d2/2
            #pragma unroll
            for (int mt = 0; mt < 2; ++mt)
                #pragma unroll
                for (int nt = 0; nt < 4; ++nt) {
                    v4f a = __builtin_amdgcn_mfma_f32_16x16x32_bf16(an[mt], bnorm[c][nt], z4, 0, 0, 0);
                    a = __builtin_amdgcn_mfma_f32_16x16x32_bf16(af[mt][0], bfr[c][nt][0], a, 0, 0, 0);
                    a = __builtin_amdgcn_mfma_f32_16x16x32_bf16(af[mt][1], bfr[c][nt][1], a, 0, 0, 0);
                    #pragma unroll
                    for (int g = 0; g < 4; ++g)
                        sums[mt][nt][g] += __builtin_amdgcn_sqrtf(fmaxf(-a[g], 0.f));
                }
        }
        #pragma unroll
        for (int mt = 0; mt < 2; ++mt)
            #pragma unroll
            for (int nt = 0; nt < 4; ++nt)
                #pragma unroll
                for (int g = 0; g < 4; ++g)
                    mins[nt] = fminf(mins[nt], sums[mt][nt][g]);
    }

    //=== Reduce across quads (same n, different w-rows), waves, then atomicMin ===
    #pragma unroll
    for (int nt = 0; nt < 4; ++nt) {
        mins[nt] = fminf(mins[nt], __shfl_xor(mins[nt], 16));
        mins[nt] = fminf(mins[nt], __shfl_xor(mins[nt], 32));
    }
    if (lane < 16) {
        #pragma unroll
        for (int nt = 0; nt < 4; ++nt) red[wave][nt * 16 + m] = mins[nt];
    }
    __syncthreads();
    if (tid < 64) {
        float v = fminf(fminf(red[0][tid], red[1][tid]),
                        fminf(red[2][tid], red[3][tid]));
        atomicMin(out_u + (size_t)b * N_ + n0 + tid,
                  __float_as_uint(v * 1.41421356237f));
    }
}

extern "C" void kernel_launch(void* const* d_in, const int* in_sizes, int n_in,
                              void* d_out, int out_size, void* d_ws, size_t ws_size,
                              hipStream_t stream) {
    const float* x   = (const float*)d_in[0];   // (64, 3, 2048) fp32
    const float* shp = (const float*)d_in[1];   // (3, 256, 64) fp32
    u32* out_u       = (u32*)d_out;             // (64, 1, 256) fp32 via u32 atomicMin

    char* ws = (char*)d_ws;
    u16* gx    = (u16*)(ws + OFF_GX);
    u16* gnorm = (u16*)(ws + OFF_NORM);
    u16* gshp  = (u16*)(ws + OFF_SHP);
    float* ghs = (float*)(ws + OFF_HS);

    hipLaunchKernelGGL(prep_kernel, dim3(451), dim3(256), 0, stream,
                       x, shp, gx, gnorm, gshp, ghs, out_u);
    hipLaunchKernelGGL(shapelet_min_kernel, dim3(512), dim3(256), 0, stream,
                       gx, gnorm, gshp, ghs, out_u);
}